// Round 2
// baseline (207.587 us; speedup 1.0000x reference)
//
#include <hip/hip_runtime.h>
#include <hip/hip_fp16.h>

// Problem constants (from reference)
constexpr int BATCH    = 4096;
constexpr int IN_DIM   = 1024;
constexpr int HIDDEN   = 8192;
constexpr int N_LAYERS = 6;
constexpr int OUT_DIM  = 8;
constexpr float INV_TAU = 0.1f;

// Tiling
constexpr int TB   = 4;             // batch rows per workgroup
constexpr int NTH  = 1024;          // threads per block (16 waves)
constexpr int NPT  = HIDDEN / NTH;  // neurons per thread = 8 (== OUT_DIM groups)
constexpr int NWAVES = NTH / 64;    // 16

// ---------------------------------------------------------------------------
// Kernel 1: precompute per-neuron gate coefficients c = softmax(w) @ GATE_COEF
// float4-vectorized loads; 128-thread blocks for more latency-hiding blocks.
// ---------------------------------------------------------------------------
__global__ void coef_kernel(const float* __restrict__ logic_w,
                            float4* __restrict__ coef, int n)
{
    int id = blockIdx.x * blockDim.x + threadIdx.x;
    if (id >= n) return;
    const float4* w4 = (const float4*)(logic_w + (size_t)id * 16);
    float4 wa = w4[0], wb = w4[1], wc = w4[2], wd = w4[3];
    float wv[16] = {wa.x, wa.y, wa.z, wa.w, wb.x, wb.y, wb.z, wb.w,
                    wc.x, wc.y, wc.z, wc.w, wd.x, wd.y, wd.z, wd.w};
    float m = wv[0];
#pragma unroll
    for (int i = 1; i < 16; ++i) m = fmaxf(m, wv[i]);
    float e[16];
    float s = 0.f;
#pragma unroll
    for (int i = 0; i < 16; ++i) { e[i] = expf(wv[i] - m); s += e[i]; }
    float inv = 1.f / s;
    // GATE_COEF columns (16 gates x 4 coefs)
    const float G0[16] = {0,0,0,0,0,0,0,0, 1,1,1,1,1,1,1,1};
    const float G1[16] = {0,0,1,1,0,0,1,1, -1,-1,0,0,-1,-1,0,0};
    const float G2[16] = {0,0,0,0,1,1,1,1, -1,-1,-1,-1,0,0,0,0};
    const float G3[16] = {0,1,-1,0,-1,0,-2,-1, 1,2,0,1,0,1,-1,0};
    float c0 = 0.f, c1 = 0.f, c2 = 0.f, c3 = 0.f;
#pragma unroll
    for (int i = 0; i < 16; ++i) {
        float p = e[i] * inv;
        c0 = fmaf(p, G0[i], c0);
        c1 = fmaf(p, G1[i], c1);
        c2 = fmaf(p, G2[i], c2);
        c3 = fmaf(p, G3[i], c3);
    }
    coef[id] = make_float4(c0, c1, c2, c3);
}

// gate: c0 + c1*a + c2*b + c3*a*b, per batch lane
__device__ __forceinline__ float4 gate4(float4 a, float4 b, float4 c) {
    float4 r;
    r.x = fmaf(c.w, a.x * b.x, fmaf(c.z, b.x, fmaf(c.y, a.x, c.x)));
    r.y = fmaf(c.w, a.y * b.y, fmaf(c.z, b.y, fmaf(c.y, a.y, c.x)));
    r.z = fmaf(c.w, a.z * b.z, fmaf(c.z, b.z, fmaf(c.y, a.z, c.x)));
    r.w = fmaf(c.w, a.w * b.w, fmaf(c.z, b.w, fmaf(c.y, a.w, c.x)));
    return r;
}

// pack 4 fp32 batch rows -> 4 fp16 in a uint2 (one ds_*_b64)
__device__ __forceinline__ uint2 pack4(float4 v) {
    __half2 lo = __float22half2_rn(make_float2(v.x, v.y));
    __half2 hi = __float22half2_rn(make_float2(v.z, v.w));
    uint2 r;
    r.x = *(const unsigned int*)&lo;
    r.y = *(const unsigned int*)&hi;
    return r;
}
__device__ __forceinline__ float4 unpack4(uint2 p) {
    __half2 lo = *(const __half2*)&p.x;
    __half2 hi = *(const __half2*)&p.y;
    float2 a = __half22float2(lo);
    float2 b = __half22float2(hi);
    return make_float4(a.x, a.y, b.x, b.y);
}

// ---------------------------------------------------------------------------
// Kernel 2: whole network fused. One workgroup = TB=4 batch rows; h lives in
// LDS as fp16x4 (uint2) [HIDDEN] = 64 KB -> 2 blocks/CU. h values are in
// [0,1] (convex softmax mixtures of logic gates), so fp16 is safe; all
// arithmetic and the final accumulation stay fp32.
// ---------------------------------------------------------------------------
__global__ __launch_bounds__(NTH, 8) void net_kernel(
    const float*  __restrict__ x,
    const float4* __restrict__ coef,
    const int*    __restrict__ idx0_a, const int* __restrict__ idx0_b,
    const int*    __restrict__ idx_a,  const int* __restrict__ idx_b,
    const float*  __restrict__ scaler_w, const float* __restrict__ scaler_b,
    float* __restrict__ out)
{
    __shared__ uint2 h[HIDDEN];             // 64 KB: 4 fp16 batch rows / neuron
    __shared__ uint2 hx[IN_DIM];            // 8 KB : binarized input
    __shared__ float partials[NWAVES][OUT_DIM][TB]; // 2 KB
    __shared__ float vals[TB][OUT_DIM];     // 128 B

    const int tid = threadIdx.x;
    const int b0  = blockIdx.x * TB;

    // Load + binarize input tile (NTH == IN_DIM: one column per thread)
    {
        float4 xv;
        xv.x = (x[(size_t)(b0 + 0) * IN_DIM + tid] > 0.5f) ? 1.f : 0.f;
        xv.y = (x[(size_t)(b0 + 1) * IN_DIM + tid] > 0.5f) ? 1.f : 0.f;
        xv.z = (x[(size_t)(b0 + 2) * IN_DIM + tid] > 0.5f) ? 1.f : 0.f;
        xv.w = (x[(size_t)(b0 + 3) * IN_DIM + tid] > 0.5f) ? 1.f : 0.f;
        hx[tid] = pack4(xv);                // 0/1 exact in fp16
    }
    __syncthreads();

    float4 acc[NPT];

    // Layer 0: gather from hx (IN_DIM), write h (HIDDEN) — disjoint regions
#pragma unroll
    for (int k = 0; k < NPT; ++k) {
        int j = k * NTH + tid;
        float4 a = unpack4(hx[idx0_a[j]]);
        float4 b = unpack4(hx[idx0_b[j]]);
        float4 c = coef[j];
        acc[k] = gate4(a, b, c);
    }
#pragma unroll
    for (int k = 0; k < NPT; ++k) h[k * NTH + tid] = pack4(acc[k]);
    __syncthreads();

    // Layers 1..5: in-place on h. Reads complete (registers) before writes.
    for (int l = 1; l < N_LAYERS; ++l) {
        const int*    ja = idx_a + (size_t)(l - 1) * HIDDEN;
        const int*    jb = idx_b + (size_t)(l - 1) * HIDDEN;
        const float4* cf = coef  + (size_t)l * HIDDEN;
#pragma unroll
        for (int k = 0; k < NPT; ++k) {
            int j = k * NTH + tid;
            float4 a = unpack4(h[ja[j]]);
            float4 b = unpack4(h[jb[j]]);
            float4 c = cf[j];
            acc[k] = gate4(a, b, c);
        }
        __syncthreads();                    // all reads of h done
        if (l != N_LAYERS - 1) {            // last layer stays in registers
#pragma unroll
            for (int k = 0; k < NPT; ++k) h[k * NTH + tid] = pack4(acc[k]);
            __syncthreads();
        }
    }

    // Epilogue: neuron j = k*1024 + tid belongs to output group o = k.
    // acc is fp32 throughout (last layer never rounded to fp16).
    const int lane = tid & 63;
    const int wv   = tid >> 6;
#pragma unroll
    for (int k = 0; k < NPT; ++k) {
        float4 v = acc[k];
#pragma unroll
        for (int off = 32; off > 0; off >>= 1) {
            v.x += __shfl_down(v.x, off);
            v.y += __shfl_down(v.y, off);
            v.z += __shfl_down(v.z, off);
            v.w += __shfl_down(v.w, off);
        }
        if (lane == 0) {
            partials[wv][k][0] = v.x;
            partials[wv][k][1] = v.y;
            partials[wv][k][2] = v.z;
            partials[wv][k][3] = v.w;
        }
    }
    __syncthreads();
    if (tid < TB * OUT_DIM) {               // 32 threads finish
        int t  = tid >> 3;                  // batch row in tile
        int oo = tid & 7;                   // output index
        float s = 0.f;
#pragma unroll
        for (int w2 = 0; w2 < NWAVES; ++w2) s += partials[w2][oo][t];
        vals[t][oo] = s * INV_TAU;
    }
    __syncthreads();
    if (tid < TB * OUT_DIM) {
        int t  = tid >> 3;
        int oo = tid & 7;
        float q = scaler_b[oo];
#pragma unroll
        for (int o2 = 0; o2 < OUT_DIM; ++o2)
            q = fmaf(vals[t][o2], scaler_w[oo * OUT_DIM + o2], q);
        out[(size_t)(b0 + t) * OUT_DIM + oo] = q;
    }
}

extern "C" void kernel_launch(void* const* d_in, const int* in_sizes, int n_in,
                              void* d_out, int out_size, void* d_ws, size_t ws_size,
                              hipStream_t stream)
{
    const float* x        = (const float*)d_in[0];
    const float* logic_w  = (const float*)d_in[1];
    const float* scaler_w = (const float*)d_in[2];
    const float* scaler_b = (const float*)d_in[3];
    const int*   idx0_a   = (const int*)d_in[4];
    const int*   idx0_b   = (const int*)d_in[5];
    const int*   idx_a    = (const int*)d_in[6];
    const int*   idx_b    = (const int*)d_in[7];
    float*  out  = (float*)d_out;
    float4* coef = (float4*)d_ws;           // 6*8192*16 B = 768 KB scratch

    const int n = N_LAYERS * HIDDEN;
    coef_kernel<<<(n + 127) / 128, 128, 0, stream>>>(logic_w, coef, n);
    net_kernel<<<BATCH / TB, NTH, 0, stream>>>(x, coef, idx0_a, idx0_b,
                                               idx_a, idx_b, scaler_w, scaler_b, out);
}

// Round 3
// 129.445 us; speedup vs baseline: 1.6037x; 1.6037x over previous
//
#include <hip/hip_runtime.h>
#include <hip/hip_fp16.h>

// Problem constants (from reference)
constexpr int BATCH    = 4096;
constexpr int IN_DIM   = 1024;
constexpr int HIDDEN   = 8192;
constexpr int N_LAYERS = 6;
constexpr int OUT_DIM  = 8;
constexpr float INV_TAU = 0.1f;

// Tiling
constexpr int TB   = 4;             // batch rows per workgroup
constexpr int NTH  = 1024;          // threads per block (16 waves)
constexpr int NPT  = HIDDEN / NTH;  // neurons per thread = 8 (== OUT_DIM groups)
constexpr int NWAVES = NTH / 64;    // 16

// pack 4 fp32 -> 4 fp16 in a uint2
__device__ __forceinline__ uint2 pack4(float4 v) {
    __half2 lo = __float22half2_rn(make_float2(v.x, v.y));
    __half2 hi = __float22half2_rn(make_float2(v.z, v.w));
    uint2 r;
    r.x = *(const unsigned int*)&lo;
    r.y = *(const unsigned int*)&hi;
    return r;
}
__device__ __forceinline__ float4 unpack4(uint2 p) {
    __half2 lo = *(const __half2*)&p.x;
    __half2 hi = *(const __half2*)&p.y;
    float2 a = __half22float2(lo);
    float2 b = __half22float2(hi);
    return make_float4(a.x, a.y, b.x, b.y);
}

// ---------------------------------------------------------------------------
// Kernel 1: precompute packed per-neuron records for all layers:
//   coefp[l*H+j] = 4 fp16 gate coefs (softmax(w) @ GATE_COEF)
//   idxp [l*H+j] = ia | (ib << 16)   (both < 8192, fit uint16)
// ---------------------------------------------------------------------------
__global__ void prep_kernel(const float* __restrict__ logic_w,
                            const int* __restrict__ idx0_a,
                            const int* __restrict__ idx0_b,
                            const int* __restrict__ idx_a,
                            const int* __restrict__ idx_b,
                            uint2* __restrict__ coefp,
                            unsigned int* __restrict__ idxp, int n)
{
    int id = blockIdx.x * blockDim.x + threadIdx.x;
    if (id >= n) return;
    const int l = id / HIDDEN;
    const int j = id - l * HIDDEN;

    // --- pack indices ---
    int ia, ib;
    if (l == 0) { ia = idx0_a[j]; ib = idx0_b[j]; }
    else        { ia = idx_a[(size_t)(l - 1) * HIDDEN + j];
                  ib = idx_b[(size_t)(l - 1) * HIDDEN + j]; }
    idxp[id] = (unsigned int)ia | ((unsigned int)ib << 16);

    // --- softmax(w) @ GATE_COEF ---
    const float4* w4 = (const float4*)(logic_w + (size_t)id * 16);
    float4 wa = w4[0], wb = w4[1], wc = w4[2], wd = w4[3];
    float wv[16] = {wa.x, wa.y, wa.z, wa.w, wb.x, wb.y, wb.z, wb.w,
                    wc.x, wc.y, wc.z, wc.w, wd.x, wd.y, wd.z, wd.w};
    float m = wv[0];
#pragma unroll
    for (int i = 1; i < 16; ++i) m = fmaxf(m, wv[i]);
    float e[16];
    float s = 0.f;
#pragma unroll
    for (int i = 0; i < 16; ++i) { e[i] = expf(wv[i] - m); s += e[i]; }
    float inv = 1.f / s;
    const float G0[16] = {0,0,0,0,0,0,0,0, 1,1,1,1,1,1,1,1};
    const float G1[16] = {0,0,1,1,0,0,1,1, -1,-1,0,0,-1,-1,0,0};
    const float G2[16] = {0,0,0,0,1,1,1,1, -1,-1,-1,-1,0,0,0,0};
    const float G3[16] = {0,1,-1,0,-1,0,-2,-1, 1,2,0,1,0,1,-1,0};
    float c0 = 0.f, c1 = 0.f, c2 = 0.f, c3 = 0.f;
#pragma unroll
    for (int i = 0; i < 16; ++i) {
        float p = e[i] * inv;
        c0 = fmaf(p, G0[i], c0);
        c1 = fmaf(p, G1[i], c1);
        c2 = fmaf(p, G2[i], c2);
        c3 = fmaf(p, G3[i], c3);
    }
    coefp[id] = pack4(make_float4(c0, c1, c2, c3));
}

// gate: c0 + c1*a + c2*b + c3*a*b, per batch lane
__device__ __forceinline__ float4 gate4(float4 a, float4 b, float4 c) {
    float4 r;
    r.x = fmaf(c.w, a.x * b.x, fmaf(c.z, b.x, fmaf(c.y, a.x, c.x)));
    r.y = fmaf(c.w, a.y * b.y, fmaf(c.z, b.y, fmaf(c.y, a.y, c.x)));
    r.z = fmaf(c.w, a.z * b.z, fmaf(c.z, b.z, fmaf(c.y, a.z, c.x)));
    r.w = fmaf(c.w, a.w * b.w, fmaf(c.z, b.w, fmaf(c.y, a.w, c.x)));
    return r;
}

// ---------------------------------------------------------------------------
// Kernel 2: fused network. TB=4 batch rows/block, h = fp16x4 [HIDDEN] = 64 KB
// (+ 8 KB hx) -> 2 blocks/CU at VGPR<=64. All layers read->barrier->write.
// Epilogue: last layer already in h; stride-128 conflict-free partial sums +
// one 64-lane butterfly (wave == half an output group by construction).
// ---------------------------------------------------------------------------
__global__ __launch_bounds__(NTH) void net_kernel(
    const float*  __restrict__ x,
    const uint2*  __restrict__ coefp,
    const unsigned int* __restrict__ idxp,
    const float*  __restrict__ scaler_w, const float* __restrict__ scaler_b,
    float* __restrict__ out)
{
    __shared__ uint2 h[HIDDEN];             // 64 KB: 4 fp16 batch rows / neuron
    __shared__ uint2 hx[IN_DIM];            // 8 KB : binarized input
    __shared__ float4 warr[NWAVES];         // 256 B: per-wave half-group sums
    __shared__ float  vals[TB][OUT_DIM];    // 128 B

    const int tid = threadIdx.x;
    const int b0  = blockIdx.x * TB;

    // Load + binarize input tile (NTH == IN_DIM: one column per thread)
    {
        float4 xv;
        xv.x = (x[(size_t)(b0 + 0) * IN_DIM + tid] > 0.5f) ? 1.f : 0.f;
        xv.y = (x[(size_t)(b0 + 1) * IN_DIM + tid] > 0.5f) ? 1.f : 0.f;
        xv.z = (x[(size_t)(b0 + 2) * IN_DIM + tid] > 0.5f) ? 1.f : 0.f;
        xv.w = (x[(size_t)(b0 + 3) * IN_DIM + tid] > 0.5f) ? 1.f : 0.f;
        hx[tid] = pack4(xv);                // 0/1 exact in fp16
    }
    __syncthreads();

    uint2 acc[NPT];                          // fp16-packed: 16 VGPRs

    // Layer 0: gather from hx (IN_DIM)
#pragma unroll
    for (int k = 0; k < NPT; ++k) {
        int j = k * NTH + tid;
        unsigned int pr = idxp[j];
        float4 a = unpack4(hx[pr & 0xffffu]);
        float4 b = unpack4(hx[pr >> 16]);
        float4 c = unpack4(coefp[j]);
        acc[k] = pack4(gate4(a, b, c));
    }
#pragma unroll
    for (int k = 0; k < NPT; ++k) h[k * NTH + tid] = acc[k];
    __syncthreads();

    // Layers 1..5: in-place on h (reads land in regs before writes)
    for (int l = 1; l < N_LAYERS; ++l) {
        const unsigned int* ip = idxp  + (size_t)l * HIDDEN;
        const uint2*        cp = coefp + (size_t)l * HIDDEN;
#pragma unroll
        for (int k = 0; k < NPT; ++k) {
            int j = k * NTH + tid;
            unsigned int pr = ip[j];
            float4 a = unpack4(h[pr & 0xffffu]);
            float4 b = unpack4(h[pr >> 16]);
            float4 c = unpack4(cp[j]);
            acc[k] = pack4(gate4(a, b, c));
        }
        __syncthreads();                    // all reads of h done
#pragma unroll
        for (int k = 0; k < NPT; ++k) h[k * NTH + tid] = acc[k];
        __syncthreads();
    }

    // Epilogue. Thread tid sums 8 neurons of group k = tid>>7 at stride 128:
    // j = k*1024 + (tid&127) + 128*i  (lane-consecutive addresses: no conflicts)
    {
        const int k    = tid >> 7;
        const int base = k * 1024 + (tid & 127);
        float4 v = make_float4(0.f, 0.f, 0.f, 0.f);
#pragma unroll
        for (int i = 0; i < 8; ++i) {
            float4 t = unpack4(h[base + 128 * i]);
            v.x += t.x; v.y += t.y; v.z += t.z; v.w += t.w;
        }
        // wave = 64 consecutive tids -> all same k; butterfly to lane 0
#pragma unroll
        for (int off = 32; off > 0; off >>= 1) {
            v.x += __shfl_down(v.x, off);
            v.y += __shfl_down(v.y, off);
            v.z += __shfl_down(v.z, off);
            v.w += __shfl_down(v.w, off);
        }
        if ((tid & 63) == 0) warr[tid >> 6] = v;   // wave wv covers half group k=wv>>1
    }
    __syncthreads();
    if (tid < OUT_DIM) {                    // 8 threads: combine the two half-groups
        float4 a = warr[2 * tid], b = warr[2 * tid + 1];
        vals[0][tid] = (a.x + b.x) * INV_TAU;
        vals[1][tid] = (a.y + b.y) * INV_TAU;
        vals[2][tid] = (a.z + b.z) * INV_TAU;
        vals[3][tid] = (a.w + b.w) * INV_TAU;
    }
    __syncthreads();
    if (tid < TB * OUT_DIM) {               // 32 threads: q = values @ W^T + b
        int t  = tid >> 3;
        int oo = tid & 7;
        float q = scaler_b[oo];
#pragma unroll
        for (int o2 = 0; o2 < OUT_DIM; ++o2)
            q = fmaf(vals[t][o2], scaler_w[oo * OUT_DIM + o2], q);
        out[(size_t)(b0 + t) * OUT_DIM + oo] = q;
    }
}

extern "C" void kernel_launch(void* const* d_in, const int* in_sizes, int n_in,
                              void* d_out, int out_size, void* d_ws, size_t ws_size,
                              hipStream_t stream)
{
    const float* x        = (const float*)d_in[0];
    const float* logic_w  = (const float*)d_in[1];
    const float* scaler_w = (const float*)d_in[2];
    const float* scaler_b = (const float*)d_in[3];
    const int*   idx0_a   = (const int*)d_in[4];
    const int*   idx0_b   = (const int*)d_in[5];
    const int*   idx_a    = (const int*)d_in[6];
    const int*   idx_b    = (const int*)d_in[7];
    float* out = (float*)d_out;

    const int n = N_LAYERS * HIDDEN;                 // 49152
    uint2*        coefp = (uint2*)d_ws;              // 384 KB
    unsigned int* idxp  = (unsigned int*)((char*)d_ws + (size_t)n * sizeof(uint2)); // 192 KB

    prep_kernel<<<(n + 255) / 256, 256, 0, stream>>>(logic_w, idx0_a, idx0_b,
                                                     idx_a, idx_b, coefp, idxp, n);
    net_kernel<<<BATCH / TB, NTH, 0, stream>>>(x, coefp, idxp,
                                               scaler_w, scaler_b, out);
}